// Round 2
// baseline (238.648 us; speedup 1.0000x reference)
//
#include <hip/hip_runtime.h>
#include <hip/hip_bf16.h>

#define BATCH 8
#define CIN 1024
#define HW2 9216
#define COUT 256
#define NSH 4
#define RHID 64
#define CPG 8
#define EPSV 1e-5f

typedef __attribute__((ext_vector_type(8))) short bf16x8;
typedef __attribute__((ext_vector_type(4))) float f32x4;

__device__ __forceinline__ unsigned short f2bf(float f) {
  unsigned u = __builtin_bit_cast(unsigned, f);
  u = (u + 0x7fffu + ((u >> 16) & 1u)) >> 16;
  return (unsigned short)u;
}

// ---------------- kernel 1: global average pool (sums) ----------------------
__global__ __launch_bounds__(256) void k_pool(
    const float* __restrict__ feat, float* __restrict__ pooled) {
  int blk = blockIdx.x;            // 73728 = 8192 rows * 9 segs
  int row = blk / 9;               // b*CIN + c
  int seg = blk - row * 9;
  long base = (long)row * HW2 + seg * 1024 + threadIdx.x * 4;
  float4 v = *(const float4*)(feat + base);
  float s = v.x + v.y + v.z + v.w;
  #pragma unroll
  for (int off = 32; off > 0; off >>= 1) s += __shfl_down(s, off);
  __shared__ float ls[4];
  if ((threadIdx.x & 63) == 0) ls[threadIdx.x >> 6] = s;
  __syncthreads();
  if (threadIdx.x == 0) atomicAdd(&pooled[row], ls[0] + ls[1] + ls[2] + ls[3]);
}

// ---------------- kernel 2a: SE mlp -> s[b][4] ------------------------------
__global__ __launch_bounds__(256) void k_se(
    const float* __restrict__ pooled, const float* __restrict__ w1,
    const float* __restrict__ b1, const float* __restrict__ w2,
    const float* __restrict__ b2, float* __restrict__ sg) {
  int b = blockIdx.x;
  int r = threadIdx.x & 63, q = threadIdx.x >> 6;
  const float* pp = pooled + b * CIN + q * 256;
  const float* wrow = w1 + (size_t)r * CIN + q * 256;
  float acc = 0.f;
  for (int c = 0; c < 256; ++c) acc += pp[c] * wrow[c];
  __shared__ float part[4][64];
  __shared__ float hid[64];
  part[q][r] = acc;
  __syncthreads();
  if (q == 0) {
    float h = (part[0][r] + part[1][r] + part[2][r] + part[3][r]) *
                  (1.f / (float)HW2) + b1[r];
    hid[r] = h > 0.f ? h : 0.f;
  }
  __syncthreads();
  if (threadIdx.x < NSH) {
    float a = 0.f;
    for (int k = 0; k < RHID; ++k) a += hid[k] * w2[threadIdx.x * RHID + k];
    a += b2[threadIdx.x];
    sg[b * NSH + threadIdx.x] = 1.f / (1.f + expf(-a));
  }
}

// ---------------- kernel 2b: conv_weight[b][o][i] = bf16(s[b][i>>8]*w_red) --
__global__ __launch_bounds__(256) void k_cw(
    const float* __restrict__ w_red, const float* __restrict__ sg,
    unsigned short* __restrict__ cw) {
  int e4 = (blockIdx.x * 256 + threadIdx.x) * 4;   // < 8*256*1024
  int b = e4 >> 18;
  int rem = e4 & 262143;
  int i = rem & 1023;
  float sv = sg[b * NSH + (i >> 8)];
  float4 v = *(const float4*)(w_red + rem);
  ushort4 o;
  o.x = f2bf(v.x * sv); o.y = f2bf(v.y * sv);
  o.z = f2bf(v.z * sv); o.w = f2bf(v.w * sv);
  *(ushort4*)(cw + e4) = o;
}

// ---------------- kernel 3: batched GEMM x[b] = cw[b] @ feat[b] -------------
// BM=256 (all of COUT), BN=128, BK=32. 512 threads = 8 waves (4M x 2N),
// each wave owns a 64x64 output tile = 4x4 fragments of 16x16.
__device__ __forceinline__ void gl16(const void* g, void* l) {
  __builtin_amdgcn_global_load_lds(
      (const __attribute__((address_space(1))) unsigned int*)g,
      (__attribute__((address_space(3))) unsigned int*)l, 16, 0, 0);
}

__global__ __launch_bounds__(512) void k_gemm(
    const float* __restrict__ feat, const unsigned short* __restrict__ cw,
    float* __restrict__ out) {
  __shared__ unsigned short As[256 * 32];   // [m][k] row-major, linear (gl_lds)
  __shared__ unsigned short BsT[128 * 32];  // [n][k], k-blocks XOR-swizzled
  const int nt = blockIdx.x, b = blockIdx.y;
  const int p0 = nt * 128;
  const int tid = threadIdx.x;
  const int lane = tid & 63, w = tid >> 6;
  const int wr = w >> 1, wc = w & 1;          // 4 x 2 wave grid
  const unsigned short* cwb = cw + (size_t)b * COUT * CIN;
  const float* fbb = feat + (size_t)b * CIN * HW2;

  // B-staging assignment: n = tid&127, kblk = tid>>7 (8 k's per thread)
  const int sn = tid & 127;
  const int skb = tid >> 7;
  const int sswz = (sn & 3) ^ ((sn >> 2) & 3);
  const float* bsrc0 = fbb + (size_t)(skb * 8) * HW2 + p0 + sn;

  f32x4 acc[4][4] = {};

  for (int k0 = 0; k0 < CIN; k0 += 32) {
    __syncthreads();  // previous tile's LDS reads complete
    // ---- stage A (bf16 cw) via global_load_lds, linear dest ----
    #pragma unroll
    for (int q = 0; q < 2; ++q) {
      int t = q * 512 + tid;   // chunk id: row=t>>2, kcol=(t&3)*8
      gl16(cwb + (t >> 2) * CIN + k0 + (t & 3) * 8,
           &As[(q * 512 + w * 64) * 8]);
    }
    // ---- stage B: fp32 feat -> bf16, transposed into BsT[n][k] ----
    {
      const float* src = bsrc0 + (size_t)k0 * HW2;
      float v[8];
      #pragma unroll
      for (int j = 0; j < 8; ++j) v[j] = src[(size_t)j * HW2];
      bf16x8 pk;
      #pragma unroll
      for (int j = 0; j < 8; ++j) pk[j] = (short)f2bf(v[j]);
      *(bf16x8*)&BsT[sn * 32 + ((skb ^ sswz) * 8)] = pk;
    }
    __syncthreads();  // compiler drains vmcnt/lgkmcnt before barrier

    // ---- fragments ----
    bf16x8 af[4];
    #pragma unroll
    for (int mi = 0; mi < 4; ++mi) {
      int row = wr * 64 + mi * 16 + (lane & 15);
      af[mi] = *(const bf16x8*)&As[row * 32 + (lane >> 4) * 8];
    }
    bf16x8 bfv[4];
    #pragma unroll
    for (int ni = 0; ni < 4; ++ni) {
      int n = wc * 64 + ni * 16 + (lane & 15);
      int swz = (n & 3) ^ ((n >> 2) & 3);
      bfv[ni] = *(const bf16x8*)&BsT[n * 32 + (((lane >> 4) ^ swz) * 8)];
    }
    #pragma unroll
    for (int mi = 0; mi < 4; ++mi)
      #pragma unroll
      for (int ni = 0; ni < 4; ++ni)
        acc[mi][ni] = __builtin_amdgcn_mfma_f32_16x16x32_bf16(
            af[mi], bfv[ni], acc[mi][ni], 0, 0, 0);
  }

  // C/D layout (verified m89): col = lane&15, row = (lane>>4)*4 + j
  float* ob = out + (size_t)b * COUT * HW2;
  #pragma unroll
  for (int mi = 0; mi < 4; ++mi) {
    int orow = wr * 64 + mi * 16 + ((lane >> 4) << 2);
    #pragma unroll
    for (int ni = 0; ni < 4; ++ni) {
      int p = p0 + wc * 64 + ni * 16 + (lane & 15);
      #pragma unroll
      for (int j = 0; j < 4; ++j)
        ob[(size_t)(orow + j) * HW2 + p] = acc[mi][ni][j];
    }
  }
}

// ---------------- kernel 4: GN stats per (b,group) --------------------------
__global__ __launch_bounds__(256) void k_stats(const float* __restrict__ x,
                                               float2* __restrict__ st) {
  int bg = blockIdx.x;  // 256 = 8b * 32g; group data contiguous (8 rows)
  const float* base = x + (size_t)bg * (CPG * HW2);
  float s1 = 0.f, s2 = 0.f;
  #pragma unroll 4
  for (int i = threadIdx.x * 4; i < CPG * HW2; i += 1024) {
    float4 v = *(const float4*)(base + i);
    s1 += v.x + v.y + v.z + v.w;
    s2 += v.x * v.x + v.y * v.y + v.z * v.z + v.w * v.w;
  }
  #pragma unroll
  for (int off = 32; off > 0; off >>= 1) {
    s1 += __shfl_down(s1, off);
    s2 += __shfl_down(s2, off);
  }
  __shared__ float a1[4], a2[4];
  if ((threadIdx.x & 63) == 0) { a1[threadIdx.x >> 6] = s1; a2[threadIdx.x >> 6] = s2; }
  __syncthreads();
  if (threadIdx.x == 0) {
    float S1 = a1[0] + a1[1] + a1[2] + a1[3];
    float S2 = a2[0] + a2[1] + a2[2] + a2[3];
    const float inv = 1.f / (float)(CPG * HW2);
    float mu = S1 * inv;
    float var = S2 * inv - mu * mu;
    st[bg] = make_float2(mu, rsqrtf(var + EPSV));
  }
}

// ---------------- kernel 5: in-place GN apply + ReLU ------------------------
__global__ __launch_bounds__(256) void k_apply(
    float* __restrict__ x, const float2* __restrict__ st,
    const float* __restrict__ gamma, const float* __restrict__ beta) {
  size_t i4 = ((size_t)blockIdx.x * 256 + threadIdx.x) * 4;
  int row = (int)(i4 / HW2);      // b*256 + o
  int o = row & 255;
  float2 s = st[row >> 3];        // b*32 + o/8
  float g = gamma[o] * s.y;
  float bb = beta[o] - s.x * g;
  float4 v = *(float4*)(x + i4);
  v.x = fmaxf(v.x * g + bb, 0.f);
  v.y = fmaxf(v.y * g + bb, 0.f);
  v.z = fmaxf(v.z * g + bb, 0.f);
  v.w = fmaxf(v.w * g + bb, 0.f);
  *(float4*)(x + i4) = v;
}

extern "C" void kernel_launch(void* const* d_in, const int* in_sizes, int n_in,
                              void* d_out, int out_size, void* d_ws, size_t ws_size,
                              hipStream_t stream) {
  const float* feat  = (const float*)d_in[0];
  const float* w1    = (const float*)d_in[1];
  const float* b1    = (const float*)d_in[2];
  const float* w2    = (const float*)d_in[3];
  const float* b2    = (const float*)d_in[4];
  const float* w_red = (const float*)d_in[5];
  const float* gamma = (const float*)d_in[6];
  const float* beta  = (const float*)d_in[7];
  float* out = (float*)d_out;

  char* ws = (char*)d_ws;
  unsigned short* cw = (unsigned short*)ws;           //  4,194,304 B
  float* pooled = (float*)(ws + 4194304);             //     32,768 B
  float* sg     = (float*)(ws + 4227072);             //        128 B
  float2* st    = (float2*)(ws + 4227200);            //      2,048 B
  // total ws need: ~4.23 MB

  hipMemsetAsync(pooled, 0, 8192 * sizeof(float), stream);
  k_pool<<<73728, 256, 0, stream>>>(feat, pooled);
  k_se<<<8, 256, 0, stream>>>(pooled, w1, b1, w2, b2, sg);
  k_cw<<<2048, 256, 0, stream>>>(w_red, sg, cw);
  k_gemm<<<dim3(72, 8), 512, 0, stream>>>(feat, cw, out);
  k_stats<<<256, 256, 0, stream>>>(out, st);
  k_apply<<<18432, 256, 0, stream>>>(out, st, gamma, beta);
}